// Round 4
// baseline (598.047 us; speedup 1.0000x reference)
//
#include <hip/hip_runtime.h>
#include <hip/hip_bf16.h>
#include <stdint.h>

// out = softmax( softmax( (q@Wq.T+bq) @ (k@Wk.T+bk).T * s ) * softmax(coarse) ) @ (v@Wv.T+bv)
// Key identity: logits = q @ (kp@Wq).T + bq.kp.T  -> removes the N x 512 x 512 GEMM entirely.
//
// ws layout (bytes):
//   kp  fp32 [100][512] @ 0        (204800)
//   Mq  bf16 [128][512] @ 204800   (131072)   rows >=100 zero
//   vpT bf16 [512][128] @ 335872   (131072)   cols >=100 zero
//   bc  fp32 [128]      @ 466944   (512)

#define WS_KP   0
#define WS_M    204800
#define WS_VPT  335872
#define WS_BC   466944

#define SCALE 0.04419417382415922f   // 1/sqrt(512)

typedef short bf16x8 __attribute__((ext_vector_type(8)));
typedef float f32x4  __attribute__((ext_vector_type(4)));
typedef unsigned int u32x2 __attribute__((ext_vector_type(2)));
typedef unsigned int u32x4 __attribute__((ext_vector_type(4)));

__device__ __forceinline__ unsigned short f2bf(float x) {
  union { float f; unsigned int u; } v; v.f = x;
  return (unsigned short)((v.u + 0x7FFFu + ((v.u >> 16) & 1u)) >> 16);
}

// ---------------- prep 1: kp = k@Wk.T+bk (fp32), vpT = (v@Wv.T+bv).T (bf16, padded) ----
__global__ void prep_kv(const float* __restrict__ kk, const float* __restrict__ vv,
                        const float* __restrict__ Wk, const float* __restrict__ bk,
                        const float* __restrict__ Wv, const float* __restrict__ bv,
                        float* __restrict__ kp, unsigned short* __restrict__ vpT) {
  __shared__ float wrow[512];
  const int o = blockIdx.x & 511;
  const bool doV = blockIdx.x >= 512;
  const float* W = doV ? Wv : Wk;
  for (int i = threadIdx.x; i < 512; i += 256) wrow[i] = W[(size_t)o * 512 + i];
  __syncthreads();
  const int c = threadIdx.x;
  float res = 0.f;
  if (c < 100) {
    const float4* s4 = (const float4*)((doV ? vv : kk) + (size_t)c * 512);
    const float4* w4 = (const float4*)wrow;
    float a0 = 0.f, a1 = 0.f, a2 = 0.f, a3 = 0.f;
    #pragma unroll 4
    for (int i = 0; i < 128; i += 4) {
      float4 x0 = s4[i+0], y0 = w4[i+0]; a0 += x0.x*y0.x + x0.y*y0.y + x0.z*y0.z + x0.w*y0.w;
      float4 x1 = s4[i+1], y1 = w4[i+1]; a1 += x1.x*y1.x + x1.y*y1.y + x1.z*y1.z + x1.w*y1.w;
      float4 x2 = s4[i+2], y2 = w4[i+2]; a2 += x2.x*y2.x + x2.y*y2.y + x2.z*y2.z + x2.w*y2.w;
      float4 x3 = s4[i+3], y3 = w4[i+3]; a3 += x3.x*y3.x + x3.y*y3.y + x3.z*y3.z + x3.w*y3.w;
    }
    res = a0 + a1 + a2 + a3 + (doV ? bv[o] : bk[o]);
  }
  if (!doV) {
    if (c < 100) kp[(size_t)c * 512 + o] = res;
  } else {
    if (c < 128) vpT[(size_t)o * 128 + c] = f2bf(c < 100 ? res : 0.f);
  }
}

// ---------------- prep 2: Mq = kp@Wq (bf16, padded), bc = kp@bq ----------------------
__global__ void prep_m(const float* __restrict__ Wq, const float* __restrict__ bq,
                       const float* __restrict__ kp,
                       unsigned short* __restrict__ Mq, float* __restrict__ bcv) {
  __shared__ float kr[512];
  __shared__ float red[512];
  const int c = blockIdx.x;    // 0..127
  const int t = threadIdx.x;   // 0..511
  if (c >= 100) {
    Mq[(size_t)c * 512 + t] = 0;
    if (t == 0) bcv[c] = 0.f;
    return;
  }
  kr[t] = kp[(size_t)c * 512 + t];
  __syncthreads();
  red[t] = kr[t] * bq[t];
  __syncthreads();
  for (int s = 256; s > 0; s >>= 1) {
    if (t < s) red[t] += red[t + s];
    __syncthreads();
  }
  if (t == 0) bcv[c] = red[0];
  float a0 = 0.f, a1 = 0.f, a2 = 0.f, a3 = 0.f;
  #pragma unroll 2
  for (int o = 0; o < 512; o += 4) {   // coalesced down Wq columns
    a0 += kr[o+0] * Wq[(size_t)(o+0) * 512 + t];
    a1 += kr[o+1] * Wq[(size_t)(o+1) * 512 + t];
    a2 += kr[o+2] * Wq[(size_t)(o+2) * 512 + t];
    a3 += kr[o+3] * Wq[(size_t)(o+3) * 512 + t];
  }
  Mq[(size_t)c * 512 + t] = f2bf(a0 + a1 + a2 + a3);
}

// ---------------- fused main kernel ---------------------------------------------------
// 64 rows/block, 4 waves (16 rows each), classes padded to 128 (8 tiles of 16).
// LDS overlay (48 KB): phase1: qs[64][128]bf16 @0, Ms[128][128]bf16 @16384
//                      phase3/4: att[64][128]bf16 @0, vps[128][128]bf16 @16384
// All tiles: 256 B rows, XOR-swizzle byte ^= ((row&7)<<4) to kill 16-way ds_read conflicts.
__global__ __launch_bounds__(256, 3)
void fused_attn(const float* __restrict__ q, const float* __restrict__ cpred,
                const unsigned short* __restrict__ Mq, const unsigned short* __restrict__ vpT,
                const float* __restrict__ bc, float* __restrict__ out) {
  __shared__ __align__(16) char lds[49152];
  const int tid = threadIdx.x;
  const int l  = tid & 63;
  const int w  = tid >> 6;
  const int g  = l >> 4;    // 0..3
  const int li = l & 15;    // 0..15
  const size_t row0 = (size_t)blockIdx.x * 64;

  f32x4 acc[8];
  #pragma unroll
  for (int t = 0; t < 8; t++) acc[t] = (f32x4){0.f, 0.f, 0.f, 0.f};

  const int sr = tid >> 5;   // 0..7 staging row base
  const int sc = tid & 31;   // float4 col

  // ---- phase 1: logits = q @ Mq^T (K=512 in 4 chunks of 128) ----
  for (int kc = 0; kc < 4; kc++) {
    #pragma unroll
    for (int i = 0; i < 8; i++) {           // q fp32 -> bf16, swizzled LDS
      const int r = sr + i * 8;
      float4 val = *(const float4*)(q + (row0 + r) * 512 + kc * 128 + sc * 4);
      u32x2 p;
      p.x = (unsigned int)f2bf(val.x) | ((unsigned int)f2bf(val.y) << 16);
      p.y = (unsigned int)f2bf(val.z) | ((unsigned int)f2bf(val.w) << 16);
      *(u32x2*)(lds + r * 256 + ((sc * 8) ^ ((r & 7) << 4))) = p;
    }
    #pragma unroll
    for (int i = 0; i < 8; i++) {           // Mq chunk bf16 -> swizzled LDS
      const int s  = tid + i * 256;
      const int cr = s >> 4;
      const int jb = (s & 15) << 4;
      u32x4 val = *(const u32x4*)((const char*)Mq + (size_t)cr * 1024 + kc * 256 + jb);
      *(u32x4*)(lds + 16384 + cr * 256 + (jb ^ ((cr & 7) << 4))) = val;
    }
    __syncthreads();
    #pragma unroll
    for (int ks = 0; ks < 4; ks++) {
      const int arow = w * 16 + li;
      bf16x8 af = *(const bf16x8*)(lds + arow * 256 + ((ks * 64 + g * 16) ^ ((arow & 7) << 4)));
      #pragma unroll
      for (int t = 0; t < 8; t++) {
        const int brow = t * 16 + li;
        bf16x8 bfr = *(const bf16x8*)(lds + 16384 + brow * 256 + ((ks * 64 + g * 16) ^ ((brow & 7) << 4)));
        acc[t] = __builtin_amdgcn_mfma_f32_16x16x32_bf16(af, bfr, acc[t], 0, 0, 0);
      }
    }
    __syncthreads();
  }

  // ---- phase 2: softmax(logits) * softmax(coarse) -> softmax -> att (bf16 LDS) ----
  float bcv[8];
  #pragma unroll
  for (int t = 0; t < 8; t++) bcv[t] = bc[t * 16 + li];

  #pragma unroll
  for (int j = 0; j < 4; j++) {
    const int lrow = w * 16 + g * 4 + j;       // C-frag: row=(l>>4)*4+reg, col=l&15
    const size_t grow = row0 + lrow;
    float lg[8], e1[8], e2[8], e3[8];
    #pragma unroll
    for (int t = 0; t < 8; t++) {
      const int cls = t * 16 + li;
      lg[t] = (cls < 100) ? (acc[t][j] + bcv[t]) * SCALE : -3.0e38f;
    }
    float m1 = lg[0];
    #pragma unroll
    for (int t = 1; t < 8; t++) m1 = fmaxf(m1, lg[t]);
    #pragma unroll
    for (int s = 1; s < 16; s <<= 1) m1 = fmaxf(m1, __shfl_xor(m1, s));
    float s1 = 0.f;
    #pragma unroll
    for (int t = 0; t < 8; t++) { e1[t] = (t * 16 + li < 100) ? __expf(lg[t] - m1) : 0.f; s1 += e1[t]; }
    #pragma unroll
    for (int s = 1; s < 16; s <<= 1) s1 += __shfl_xor(s1, s);
    const float inv1 = 1.0f / s1;

    float cpv[8];
    #pragma unroll
    for (int t = 0; t < 8; t++) {
      const int cls = t * 16 + li;
      cpv[t] = (cls < 100) ? cpred[grow * 100 + cls] : -3.0e38f;
    }
    float m2 = cpv[0];
    #pragma unroll
    for (int t = 1; t < 8; t++) m2 = fmaxf(m2, cpv[t]);
    #pragma unroll
    for (int s = 1; s < 16; s <<= 1) m2 = fmaxf(m2, __shfl_xor(m2, s));
    float s2 = 0.f;
    #pragma unroll
    for (int t = 0; t < 8; t++) { e2[t] = (t * 16 + li < 100) ? __expf(cpv[t] - m2) : 0.f; s2 += e2[t]; }
    #pragma unroll
    for (int s = 1; s < 16; s <<= 1) s2 += __shfl_xor(s2, s);
    const float inv2 = 1.0f / s2;

    float x[8];
    #pragma unroll
    for (int t = 0; t < 8; t++) {
      const int cls = t * 16 + li;
      x[t] = (cls < 100) ? (e1[t] * inv1) * (e2[t] * inv2) : -3.0e38f;
    }
    float m3 = x[0];
    #pragma unroll
    for (int t = 1; t < 8; t++) m3 = fmaxf(m3, x[t]);
    #pragma unroll
    for (int s = 1; s < 16; s <<= 1) m3 = fmaxf(m3, __shfl_xor(m3, s));
    float s3 = 0.f;
    #pragma unroll
    for (int t = 0; t < 8; t++) { e3[t] = (t * 16 + li < 100) ? __expf(x[t] - m3) : 0.f; s3 += e3[t]; }
    #pragma unroll
    for (int s = 1; s < 16; s <<= 1) s3 += __shfl_xor(s3, s);
    const float inv3 = 1.0f / s3;

    #pragma unroll
    for (int t = 0; t < 8; t++) {          // att transpose-store (swizzled), zeros for pad
      const int cls = t * 16 + li;
      *(unsigned short*)(lds + lrow * 256 + ((cls * 2) ^ ((lrow & 7) << 4))) = f2bf(e3[t] * inv3);
    }
  }

  // ---- phase 4: out = att @ vpT^T (K=128), 4 col-chunks of 128 ----
  for (int dc = 0; dc < 4; dc++) {
    if (dc > 0) __syncthreads();
    #pragma unroll
    for (int i = 0; i < 8; i++) {           // stage vpT chunk, swizzled
      const int s  = tid + i * 256;
      const int rr = s >> 4;
      const int jb = (s & 15) << 4;
      u32x4 val = *(const u32x4*)((const char*)vpT + (size_t)(dc * 128 + rr) * 256 + jb);
      *(u32x4*)(lds + 16384 + rr * 256 + (jb ^ ((rr & 7) << 4))) = val;
    }
    __syncthreads();
    f32x4 facc[8];
    #pragma unroll
    for (int t = 0; t < 8; t++) facc[t] = (f32x4){0.f, 0.f, 0.f, 0.f};
    #pragma unroll
    for (int ks = 0; ks < 4; ks++) {
      const int arow = w * 16 + li;
      bf16x8 af = *(const bf16x8*)(lds + arow * 256 + ((ks * 64 + g * 16) ^ ((arow & 7) << 4)));
      #pragma unroll
      for (int t = 0; t < 8; t++) {
        const int brow = t * 16 + li;
        bf16x8 bfr = *(const bf16x8*)(lds + 16384 + brow * 256 + ((ks * 64 + g * 16) ^ ((brow & 7) << 4)));
        facc[t] = __builtin_amdgcn_mfma_f32_16x16x32_bf16(af, bfr, facc[t], 0, 0, 0);
      }
    }
    #pragma unroll
    for (int t = 0; t < 8; t++) {
      const int col = dc * 128 + t * 16 + li;
      #pragma unroll
      for (int j = 0; j < 4; j++) {
        const int lrow = w * 16 + g * 4 + j;
        out[(row0 + lrow) * 512 + col] = facc[t][j];
      }
    }
  }
}

extern "C" void kernel_launch(void* const* d_in, const int* in_sizes, int n_in,
                              void* d_out, int out_size, void* d_ws, size_t ws_size,
                              hipStream_t stream) {
  const float* q     = (const float*)d_in[0];
  const float* k     = (const float*)d_in[1];
  const float* v     = (const float*)d_in[2];
  const float* cpred = (const float*)d_in[3];
  const float* Wq    = (const float*)d_in[4];
  const float* bq    = (const float*)d_in[5];
  const float* Wk    = (const float*)d_in[6];
  const float* bk    = (const float*)d_in[7];
  const float* Wv    = (const float*)d_in[8];
  const float* bv    = (const float*)d_in[9];
  float* out = (float*)d_out;
  char* ws = (char*)d_ws;

  float*          kp  = (float*)(ws + WS_KP);
  unsigned short* Mq  = (unsigned short*)(ws + WS_M);
  unsigned short* vpT = (unsigned short*)(ws + WS_VPT);
  float*          bc  = (float*)(ws + WS_BC);

  prep_kv<<<1024, 256, 0, stream>>>(k, v, Wk, bk, Wv, bv, kp, vpT);
  prep_m<<<128, 512, 0, stream>>>(Wq, bq, kp, Mq, bc);
  fused_attn<<<131072 / 64, 256, 0, stream>>>(q, cpred, Mq, vpT, bc, out);
}